// Round 4
// baseline (3084.449 us; speedup 1.0000x reference)
//
#include <hip/hip_runtime.h>
#include <math.h>

typedef _Float16 f16;
typedef f16 f16x8 __attribute__((ext_vector_type(8)));
typedef float f32x4 __attribute__((ext_vector_type(4)));

#define NTOT 3840
#define KP   3968          // 3840 neurons + 128 inputs
#define BATCH 32
#define TSTEPS 100
#define NIN 128
#define NWG 241            // 240 column tiles of 16 + 1 readout/stage WG

__device__ __forceinline__ bool is_dend(int k){
  return (k>=512 && k<1536) || (k>=2432 && k<3456);
}
__device__ __forceinline__ bool is_inh(int k){
  return (k>=1536 && k<1920) || (k>=3456 && k<3840);
}
__device__ __forceinline__ ushort f2h(float v){ f16 h=(f16)v; return *(ushort*)&h; }
__device__ __forceinline__ float h2f(ushort u){ f16 h=*(f16*)&u; return (float)h; }

// ---------- one-time: WT[n][k] = fp16(w_eff^T), mask derived analytically ----------
__global__ __launch_bounds__(256) void k_prep_w(const float* __restrict__ w_rec,
    const float* __restrict__ w_in, ushort* __restrict__ WT){
  __shared__ ushort tile[64][72];
  const int bid = blockIdx.x;
  const int kt = bid / 60, nt = bid % 60;
  const int k0 = kt*64, n0 = nt*64;
  const int t = threadIdx.x;
  const int tr = t>>2, tq = t&3;
  const int k = k0 + tr;
  const int cbase = n0 + tq*16;
  if (k < NTOT){
    const float sgn = is_inh(k) ? -1.f : 1.f;
    const bool rowSr  = (k>=512  && k<1536);
    const bool rowPfc = (k>=2432 && k<3456);
    #pragma unroll
    for (int q=0;q<4;q++){
      float4 w = *(const float4*)(w_rec + (size_t)k*NTOT + cbase + q*4);
      float v[4] = {sgn*fabsf(w.x), sgn*fabsf(w.y), sgn*fabsf(w.z), sgn*fabsf(w.w)};
      #pragma unroll
      for (int e=0;e<4;e++){
        const int n = cbase + q*4 + e;
        if (n==k || (rowSr && n<512) || (rowPfc && n>=1920 && n<2432)) v[e]=0.f;
        tile[tr][tq*16+q*4+e] = f2h(v[e]);
      }
    }
  } else {
    const float* src = w_in + (size_t)(k-NTOT)*NTOT + cbase;
    #pragma unroll
    for (int q=0;q<4;q++){
      float4 w = *(const float4*)(src + q*4);
      tile[tr][tq*16+q*4+0] = f2h(w.x);
      tile[tr][tq*16+q*4+1] = f2h(w.y);
      tile[tr][tq*16+q*4+2] = f2h(w.z);
      tile[tr][tq*16+q*4+3] = f2h(w.w);
    }
  }
  __syncthreads();
  const int n  = n0 + tr;
  const int kq = tq*16;
  uint u[8];
  #pragma unroll
  for (int q=0;q<8;q++)
    u[q] = (uint)tile[kq+2*q][tr] | ((uint)tile[kq+2*q+1][tr] << 16);
  uint4* dst = (uint4*)(WT + (size_t)n*KP + k0 + kq);
  dst[0] = make_uint4(u[0],u[1],u[2],u[3]);
  dst[1] = make_uint4(u[4],u[5],u[6],u[7]);
}

// ---------- init: r0[b][k] (x_0 appended), barrier counter = 0 ----------
__global__ void k_init(const float* __restrict__ x, ushort* __restrict__ r0,
                       unsigned* __restrict__ bar){
  int i = blockIdx.x*blockDim.x + threadIdx.x;
  int nthr = gridDim.x*blockDim.x;
  if (i==0) *bar = 0u;
  for (int e=i; e<BATCH*KP; e+=nthr){
    int b = e / KP, k = e % KP;
    float v = (k<NTOT) ? (is_dend(k)?0.5f:0.f) : x[b*NIN + (k-NTOT)];
    r0[e] = f2h(v);
  }
}

// ---------- persistent kernel: all 100 steps, grid-wide barrier between steps ----------
// 241 WGs x 256 thr. WG<240: 16 output cols, 4 waves K-split (992 each), MFMA,
// LDS reduce, update with h/ime in REGISTERS across all steps. WG 240: readout + x-stage.
__global__ __launch_bounds__(256,1) void k_run(
    const ushort* __restrict__ WTu, ushort* __restrict__ r0u, ushort* __restrict__ r1u,
    const float* __restrict__ noise, const float* __restrict__ x,
    const float* __restrict__ bvec, const float* __restrict__ d2s,
    const float* __restrict__ w_out, const float* __restrict__ b_out,
    float* __restrict__ out, unsigned* __restrict__ bar)
{
  __shared__ f32x4 red[3][2][64];          // 6 KB
  __shared__ float pre_lds[32][16];        // 2 KB
  const f16* WT = (const f16*)WTu;
  const int bid = blockIdx.x;
  const int tid = threadIdx.x;
  const int kw = tid>>6, l = tid&63, l15 = l&15, lh = l>>4;
  const int n0 = bid*16;
  const int ub = tid>>3, uc2 = (tid&7)*2;
  const int n  = n0 + uc2;
  const float NS = 0.0063245553203367585f;           // sqrt(2*0.2)*0.01

  // persistent per-thread state
  float hr0=0.f, hr1=0.f, im0=0.f, im1=0.f;
  float bv0=0.f, bv1=0.f, dA0=0.f, dA1=0.f, dB0=0.f, dB1=0.f, al0=0.f, al1=0.f;
  bool cSR=false, cPFC=false, cME=false, dendF=false;
  if (bid < 240){
    bv0 = bvec[n]; bv1 = bvec[n+1];
    cSR  = (n0 < 512);
    cPFC = (n0 >= 1920 && n0 < 2432);
    cME  = (n0 >= 2432 && n0 < 3456);
    dendF = (n0>=512 && n0<1536) || (n0>=2432 && n0<3456);
    if (cSR){  dA0=d2s[n];        dA1=d2s[n+1];
               dB0=d2s[512+n];    dB1=d2s[512+n+1]; }
    if (cPFC){ const int j=n-1920;
               dA0=d2s[1024+j];   dA1=d2s[1024+j+1];
               dB0=d2s[1536+j];   dB1=d2s[1536+j+1]; }
    if (cME){
      const float LN10 = 2.302585092994046f;
      const float CEXP = 1.6989700043360187f/511.0f; // (log10(5000)-2)/511
      const int j = n-2432;
      al0 = expf(-LN10*(1.0f + CEXP*(float)( j   &511)));
      al1 = expf(-LN10*(1.0f + CEXP*(float)((j+1)&511)));
    }
  }

  for (int t=0; t<TSTEPS; t++){
    const ushort* rcu = (t&1) ? r1u : r0u;
    ushort*       rnu = (t&1) ? r0u : r1u;
    const f16* rc = (const f16*)rcu;

    if (bid < 240){
      // ---- MFMA: this WG's 16 cols x full K, split over 4 waves ----
      f32x4 acc[2];
      acc[0].x=0;acc[0].y=0;acc[0].z=0;acc[0].w=0;
      acc[1].x=0;acc[1].y=0;acc[1].z=0;acc[1].w=0;
      {
        const int kbase = kw*992 + lh*8;
        const f16* pa0 = rc + (size_t)l15*KP + kbase;
        const f16* pa1 = pa0 + (size_t)16*KP;
        const f16* pb0 = WT + (size_t)(n0+l15)*KP + kbase;
        #pragma unroll 4
        for (int ks=0; ks<31; ks++){
          const int ko = ks*32;
          f16x8 a0 = *(const f16x8*)(pa0 + ko);
          f16x8 a1 = *(const f16x8*)(pa1 + ko);
          f16x8 b0 = *(const f16x8*)(pb0 + ko);
          acc[0] = __builtin_amdgcn_mfma_f32_16x16x32_f16(a0, b0, acc[0], 0,0,0);
          acc[1] = __builtin_amdgcn_mfma_f32_16x16x32_f16(a1, b0, acc[1], 0,0,0);
        }
      }
      if (kw > 0){
        red[kw-1][0][l] = acc[0];
        red[kw-1][1][l] = acc[1];
      }
      __syncthreads();
      if (kw == 0){
        #pragma unroll
        for (int w=0;w<3;w++){ acc[0] += red[w][0][l]; acc[1] += red[w][1][l]; }
        // C frag: col = l&15, row(batch) = m*16 + (l>>4)*4 + reg
        #pragma unroll
        for (int m=0;m<2;m++)
          #pragma unroll
          for (int rg=0;rg<4;rg++)
            pre_lds[m*16 + lh*4 + rg][l15] = acc[m][rg];
      }
      __syncthreads();

      // ---- update: thread -> (batch ub, 2 cols) ----
      {
        float2 pv = *(const float2*)&pre_lds[ub][uc2];
        float p0 = pv.x + bv0, p1 = pv.y + bv1;
        if (cSR){
          p0 += h2f(rcu[ub*KP + 512 +n  ])*dA0 + h2f(rcu[ub*KP + 1024+n  ])*dB0;
          p1 += h2f(rcu[ub*KP + 512 +n+1])*dA1 + h2f(rcu[ub*KP + 1024+n+1])*dB1;
        } else if (cPFC){
          const int j = n-1920;
          p0 += h2f(rcu[ub*KP + 2432+j  ])*dA0 + h2f(rcu[ub*KP + 2944+j  ])*dB0;
          p1 += h2f(rcu[ub*KP + 2432+j+1])*dA1 + h2f(rcu[ub*KP + 2944+j+1])*dB1;
        }
        if (cME){
          im0 = (1.f-al0)*im0 + al0*fmaxf(p0,0.f); p0 += im0;
          im1 = (1.f-al1)*im1 + al1*fmaxf(p1,0.f); p1 += im1;
        }
        float2 nz = *(const float2*)(noise + (size_t)t*BATCH*NTOT + ub*NTOT + n);
        hr0 = 0.8f*hr0 + 0.2f*p0 + NS*nz.x;
        hr1 = 0.8f*hr1 + 0.2f*p1 + NS*nz.y;
        const float rv0 = dendF ? (1.f/(1.f+expf(-hr0))) : fmaxf(hr0,0.f);
        const float rv1 = dendF ? (1.f/(1.f+expf(-hr1))) : fmaxf(hr1,0.f);
        ushort2 st; st.x = f2h(rv0); st.y = f2h(rv1);
        *(ushort2*)&rnu[ub*KP + n] = st;
      }
    } else {
      // ---- WG 240: readout (r_t[:,0:512] @ w_out) + next-x staging ----
      if (kw < 3){
        const int o = kw, b = l>>1, half = l&1;
        const f16* rr = rc + (size_t)b*KP + half*256;
        float s = 0.f;
        #pragma unroll 8
        for (int k2=0;k2<256;k2++) s += (float)rr[k2] * w_out[(half*256+k2)*3+o];
        s += __shfl_down(s, 1);
        if (half==0) out[t*BATCH*3 + b*3+o] = s + b_out[o];
      }
      if (t+1 < TSTEPS){
        const int b = tid>>3, j = (tid&7)*16;
        const float* xs = x + (size_t)(t+1)*BATCH*NIN + b*NIN + j;
        #pragma unroll
        for (int q=0;q<4;q++){
          float4 v = *(const float4*)(xs + q*4);
          ushort4 st = {f2h(v.x),f2h(v.y),f2h(v.z),f2h(v.w)};
          *(ushort4*)&rnu[b*KP + NTOT + j + q*4] = st;
        }
      }
    }

    // ---- grid barrier (skip after last step) ----
    if (t+1 < TSTEPS){
      __syncthreads();                      // drain all threads' stores (vmcnt 0)
      if (tid == 0){
        __threadfence();                    // L2 writeback -> L3 (release)
        atomicAdd(bar, 1u);
        const unsigned target = (unsigned)NWG * (unsigned)(t+1);
        while (__hip_atomic_load(bar, __ATOMIC_RELAXED, __HIP_MEMORY_SCOPE_AGENT) < target)
          __builtin_amdgcn_s_sleep(2);
        __threadfence();                    // L2/L1 invalidate (acquire)
      }
      __syncthreads();
    }
  }
}

extern "C" void kernel_launch(void* const* d_in, const int* in_sizes, int n_in,
                              void* d_out, int out_size, void* d_ws, size_t ws_size,
                              hipStream_t stream) {
  const float* x     = (const float*)d_in[0];   // [100,32,128]
  const float* noise = (const float*)d_in[1];   // [100,32,3840]
  const float* w_rec = (const float*)d_in[2];   // [3840,3840]
  const float* w_in  = (const float*)d_in[3];   // [128,3840]
  const float* bvec  = (const float*)d_in[4];   // [3840]
  const float* d2s   = (const float*)d_in[5];   // [2048]
  const float* w_out = (const float*)d_in[6];   // [512,3]
  const float* b_out = (const float*)d_in[7];   // [3]
  // d_in[8] = mask: derived analytically
  float* out = (float*)d_out;                   // [100,32,3]

  char* ws = (char*)d_ws;
  ushort*   WT  = (ushort*)(ws);                // 30,474,240 B
  ushort*   r0  = (ushort*)(ws + 30474240);     //    253,952 B
  ushort*   r1  = (ushort*)(ws + 30728192);     //    253,952 B
  unsigned* bar = (unsigned*)(ws + 30982144);   //          4 B

  k_prep_w<<<3720,256,0,stream>>>(w_rec, w_in, WT);
  k_init<<<64,256,0,stream>>>(x, r0, bar);
  k_run<<<NWG,256,0,stream>>>(WT, r0, r1, noise, x, bvec, d2s,
                              w_out, b_out, out, bar);
}

// Round 6
// 2446.841 us; speedup vs baseline: 1.2606x; 1.2606x over previous
//
#include <hip/hip_runtime.h>
#include <math.h>

typedef _Float16 f16;
typedef f16 f16x8 __attribute__((ext_vector_type(8)));
typedef float f32x4 __attribute__((ext_vector_type(4)));

#define NTOT 3840
#define KP   3968          // 3840 neurons + 128 inputs
#define BATCH 32
#define TSTEPS 100
#define NIN 128
#define NWG 241            // 240 col-tile WGs (16 cols, 512 thr) + 1 readout WG

__device__ __forceinline__ bool is_dend(int k){
  return (k>=512 && k<1536) || (k>=2432 && k<3456);
}
__device__ __forceinline__ bool is_inh(int k){
  return (k>=1536 && k<1920) || (k>=3456 && k<3840);
}
__device__ __forceinline__ ushort f2h(float v){ f16 h=(f16)v; return *(ushort*)&h; }
__device__ __forceinline__ float h2f(ushort u){ f16 h=*(f16*)&u; return (float)h; }

// ---------- one-time: WT[n][k] = fp16(w_eff^T), mask derived analytically ----------
__global__ __launch_bounds__(256) void k_prep_w(const float* __restrict__ w_rec,
    const float* __restrict__ w_in, ushort* __restrict__ WT){
  __shared__ ushort tile[64][72];
  const int bid = blockIdx.x;
  const int kt = bid / 60, nt = bid % 60;
  const int k0 = kt*64, n0 = nt*64;
  const int t = threadIdx.x;
  const int tr = t>>2, tq = t&3;
  const int k = k0 + tr;
  const int cbase = n0 + tq*16;
  if (k < NTOT){
    const float sgn = is_inh(k) ? -1.f : 1.f;
    const bool rowSr  = (k>=512  && k<1536);
    const bool rowPfc = (k>=2432 && k<3456);
    #pragma unroll
    for (int q=0;q<4;q++){
      float4 w = *(const float4*)(w_rec + (size_t)k*NTOT + cbase + q*4);
      float v[4] = {sgn*fabsf(w.x), sgn*fabsf(w.y), sgn*fabsf(w.z), sgn*fabsf(w.w)};
      #pragma unroll
      for (int e=0;e<4;e++){
        const int n = cbase + q*4 + e;
        if (n==k || (rowSr && n<512) || (rowPfc && n>=1920 && n<2432)) v[e]=0.f;
        tile[tr][tq*16+q*4+e] = f2h(v[e]);
      }
    }
  } else {
    const float* src = w_in + (size_t)(k-NTOT)*NTOT + cbase;
    #pragma unroll
    for (int q=0;q<4;q++){
      float4 w = *(const float4*)(src + q*4);
      tile[tr][tq*16+q*4+0] = f2h(w.x);
      tile[tr][tq*16+q*4+1] = f2h(w.y);
      tile[tr][tq*16+q*4+2] = f2h(w.z);
      tile[tr][tq*16+q*4+3] = f2h(w.w);
    }
  }
  __syncthreads();
  const int n  = n0 + tr;
  const int kq = tq*16;
  uint u[8];
  #pragma unroll
  for (int q=0;q<8;q++)
    u[q] = (uint)tile[kq+2*q][tr] | ((uint)tile[kq+2*q+1][tr] << 16);
  uint4* dst = (uint4*)(WT + (size_t)n*KP + k0 + kq);
  dst[0] = make_uint4(u[0],u[1],u[2],u[3]);
  dst[1] = make_uint4(u[4],u[5],u[6],u[7]);
}

// ---------- init: r0[b][k] (x_0 appended), barrier area zeroed ----------
__global__ void k_init(const float* __restrict__ x, ushort* __restrict__ r0,
                       unsigned* __restrict__ bar){
  int i = blockIdx.x*blockDim.x + threadIdx.x;
  int nthr = gridDim.x*blockDim.x;
  for (int e=i; e<1024; e+=nthr) bar[e] = 0u;
  for (int e=i; e<BATCH*KP; e+=nthr){
    int b = e / KP, k = e % KP;
    float v = (k<NTOT) ? (is_dend(k)?0.5f:0.f) : x[b*NIN + (k-NTOT)];
    r0[e] = f2h(v);
  }
}

// ---------- persistent kernel: all 100 steps, hierarchical grid barrier ----------
// 241 WGs x 512 thr (8 waves). WG<240: 16 cols; wave (bh,kw) = batch-half x K-quarter.
// h/ime persistent in registers. WG 240: readout + x staging.
__global__ __launch_bounds__(512,1) void k_run(
    const ushort* __restrict__ WTu, ushort* r0u, ushort* r1u,
    const float* __restrict__ noise, const float* __restrict__ x,
    const float* __restrict__ bvec, const float* __restrict__ d2s,
    const float* __restrict__ w_out, const float* __restrict__ b_out,
    float* __restrict__ out, unsigned* bar)
{
  __shared__ f32x4 red[3][2][64];          // 6 KB
  __shared__ float pre_lds[32][16];        // 2 KB
  const f16* WT = (const f16*)WTu;
  const int bid = blockIdx.x;
  const int tid = threadIdx.x;
  const int wv = tid>>6, l = tid&63, l15 = l&15, lh = l>>4;
  const int bh = wv&1, kw = wv>>1;
  const int n0 = bid*16;
  const int ub = tid>>4, uc = tid&15;      // update: (batch, col)
  const int n  = n0 + uc;
  const float NS = 0.0063245553203367585f; // sqrt(2*0.2)*0.01

  // persistent per-thread state (1 column each)
  float hr=0.f, im=0.f, bv=0.f, dA=0.f, dB=0.f, al=0.f;
  bool cSR=false, cPFC=false, cME=false, dendF=false;
  if (bid < 240){
    bv = bvec[n];
    cSR  = (n0 < 512);
    cPFC = (n0 >= 1920 && n0 < 2432);
    cME  = (n0 >= 2432 && n0 < 3456);
    dendF = (n0>=512 && n0<1536) || cME;
    if (cSR){  dA=d2s[n];       dB=d2s[512+n]; }
    if (cPFC){ const int j=n-1920; dA=d2s[1024+j]; dB=d2s[1536+j]; }
    if (cME){
      const float LN10 = 2.302585092994046f;
      const float CEXP = 1.6989700043360187f/511.0f;  // (log10(5000)-2)/511
      const int j = n-2432;
      al = expf(-LN10*(1.0f + CEXP*(float)(j&511)));
    }
  }

  // hierarchical barrier bookkeeping (monotonic epochs, no resets)
  const int xg = bid & 7;                          // pseudo-XCD group
  const unsigned mycnt = (xg==0) ? 31u : 30u;      // WGs in this group
  unsigned* xcnt = bar + xg*32;                    // arrival counter (128B apart)
  unsigned* xep  = bar + 256 + xg*32;              // group epoch
  unsigned* gcnt = bar + 512;                      // global leader counter
  unsigned* gep  = bar + 544;                      // global epoch

  for (int t=0; t<TSTEPS; t++){
    const ushort* rcu = (t&1) ? r1u : r0u;
    ushort*       rnu = (t&1) ? r0u : r1u;
    const f16* rc = (const f16*)rcu;

    if (bid < 240){
      // ---- MFMA: 16 cols x 16 batch rows x K/4 per wave ----
      f32x4 acc; acc.x=0.f; acc.y=0.f; acc.z=0.f; acc.w=0.f;
      {
        const int kbase = kw*992 + lh*8;
        const f16* pa = rc + (size_t)(bh*16+l15)*KP + kbase;
        const f16* pb = WT + (size_t)(n0+l15)*KP + kbase;
        #pragma unroll 8
        for (int ks=0; ks<31; ks++){
          const int ko = ks*32;
          f16x8 a = *(const f16x8*)(pa + ko);
          f16x8 b = *(const f16x8*)(pb + ko);
          acc = __builtin_amdgcn_mfma_f32_16x16x32_f16(a, b, acc, 0,0,0);
        }
      }
      if (kw > 0) red[kw-1][bh][l] = acc;
      __syncthreads();
      if (kw == 0){
        #pragma unroll
        for (int w=0;w<3;w++) acc += red[w][bh][l];
        // C frag: col = l&15, row(batch within half) = (l>>4)*4 + reg
        #pragma unroll
        for (int rg=0;rg<4;rg++)
          pre_lds[bh*16 + lh*4 + rg][l15] = acc[rg];
      }
      __syncthreads();

      // ---- update: one (batch, col) per thread ----
      {
        float p = pre_lds[ub][uc] + bv;
        if (cSR){
          p += h2f(rcu[ub*KP + 512 +n])*dA + h2f(rcu[ub*KP + 1024+n])*dB;
        } else if (cPFC){
          const int j = n-1920;
          p += h2f(rcu[ub*KP + 2432+j])*dA + h2f(rcu[ub*KP + 2944+j])*dB;
        }
        if (cME){
          im = (1.f-al)*im + al*fmaxf(p,0.f); p += im;
        }
        const float nz = noise[(size_t)t*BATCH*NTOT + ub*NTOT + n];
        hr = 0.8f*hr + 0.2f*p + NS*nz;
        const float rv = dendF ? (1.f/(1.f+expf(-hr))) : fmaxf(hr,0.f);
        rnu[ub*KP + n] = f2h(rv);
      }
    } else {
      // ---- WG 240: readout + next-x staging ----
      if (wv < 3){
        const int o = wv, b = l>>1, half = l&1;
        const f16* rr = rc + (size_t)b*KP + half*256;
        float s = 0.f;
        #pragma unroll 8
        for (int k2=0;k2<256;k2++) s += (float)rr[k2] * w_out[(half*256+k2)*3+o];
        s += __shfl_down(s, 1);
        if (half==0) out[t*BATCH*3 + b*3+o] = s + b_out[o];
      }
      if (t+1 < TSTEPS && tid < 256){
        const int b = tid>>3, j = (tid&7)*16;
        const float* xs = x + (size_t)(t+1)*BATCH*NIN + b*NIN + j;
        #pragma unroll
        for (int q=0;q<4;q++){
          float4 v = *(const float4*)(xs + q*4);
          ushort4 st = {f2h(v.x),f2h(v.y),f2h(v.z),f2h(v.w)};
          *(ushort4*)&rnu[b*KP + NTOT + j + q*4] = st;
        }
      }
    }

    // ---- hierarchical grid barrier (skip after last step) ----
    if (t+1 < TSTEPS){
      __syncthreads();
      if (tid == 0){
        __builtin_amdgcn_fence(__ATOMIC_RELEASE, "agent");   // L2 writeback
        unsigned old = __hip_atomic_fetch_add(xcnt, 1u,
                          __ATOMIC_RELAXED, __HIP_MEMORY_SCOPE_AGENT);
        if (old == mycnt*(unsigned)(t+1) - 1u){
          // last WG of this group: arrive globally
          unsigned g = __hip_atomic_fetch_add(gcnt, 1u,
                          __ATOMIC_RELAXED, __HIP_MEMORY_SCOPE_AGENT);
          if (g == 8u*(unsigned)(t+1) - 1u){
            __hip_atomic_store(gep, (unsigned)(t+1),
                          __ATOMIC_RELAXED, __HIP_MEMORY_SCOPE_AGENT);
          } else {
            while (__hip_atomic_load(gep, __ATOMIC_RELAXED,
                          __HIP_MEMORY_SCOPE_AGENT) < (unsigned)(t+1))
              __builtin_amdgcn_s_sleep(2);
          }
          __hip_atomic_store(xep, (unsigned)(t+1),
                          __ATOMIC_RELAXED, __HIP_MEMORY_SCOPE_AGENT);
        } else {
          while (__hip_atomic_load(xep, __ATOMIC_RELAXED,
                          __HIP_MEMORY_SCOPE_AGENT) < (unsigned)(t+1))
            __builtin_amdgcn_s_sleep(2);
        }
        __builtin_amdgcn_fence(__ATOMIC_ACQUIRE, "agent");   // L1/L2 invalidate
      }
      __syncthreads();
    }
  }
}

extern "C" void kernel_launch(void* const* d_in, const int* in_sizes, int n_in,
                              void* d_out, int out_size, void* d_ws, size_t ws_size,
                              hipStream_t stream) {
  const float* x     = (const float*)d_in[0];   // [100,32,128]
  const float* noise = (const float*)d_in[1];   // [100,32,3840]
  const float* w_rec = (const float*)d_in[2];   // [3840,3840]
  const float* w_in  = (const float*)d_in[3];   // [128,3840]
  const float* bvec  = (const float*)d_in[4];   // [3840]
  const float* d2s   = (const float*)d_in[5];   // [2048]
  const float* w_out = (const float*)d_in[6];   // [512,3]
  const float* b_out = (const float*)d_in[7];   // [3]
  // d_in[8] = mask: derived analytically
  float* out = (float*)d_out;                   // [100,32,3]

  char* ws = (char*)d_ws;
  ushort*   WT  = (ushort*)(ws);                // 30,474,240 B
  ushort*   r0  = (ushort*)(ws + 30474240);     //    253,952 B
  ushort*   r1  = (ushort*)(ws + 30728192);     //    253,952 B
  unsigned* bar = (unsigned*)(ws + 30982144);   //      4,096 B

  k_prep_w<<<3720,256,0,stream>>>(w_rec, w_in, WT);
  k_init<<<64,256,0,stream>>>(x, r0, bar);
  k_run<<<NWG,512,0,stream>>>(WT, r0, r1, noise, x, bvec, d2s,
                              w_out, b_out, out, bar);
}